// Round 6
// baseline (758.428 us; speedup 1.0000x reference)
//
#include <hip/hip_runtime.h>

#define NC 100000
#define NF 400000
#define NE 1600000
#define C  64

// ============================================================================
// v7: v6 + (1) LDS-staged partition with line-granular write-out,
//          (2) GEMM fused into the coarse sortgather (k_gemm_ip deleted).
//  k_partition  : per 4096-edge tile: LDS hist(512) -> scan -> place into
//                 LDS srt[] (+u16 bucket ids) -> global reserve (1 atomic
//                 per bucket per block) -> LINEAR sweep writes full 64B
//                 lines (v6 wrote 8B scattered: up to 64 line-transactions
//                 per wave; now ~8).
//  k_sortgather : block = bucket. Records -> regs, LDS hist+scan, place to
//                 LDS sorted array, gather with one 16-lane quadrant per
//                 node. COARSE=true additionally holds W in LDS (16KB) and
//                 finishes each node with the 64x64 GEMM in-register via
//                 quadrant shuffles (agg never hits global; h = agg*W + b
//                 written once). Saves k_gemm_ip + 51MB h round trip.
// ============================================================================

#define NSUB 512                // buckets per phase
#define CAPB 4096               // records per bucket (mean ~3130)
#define SUBC 196                // dst nodes per coarse bucket
#define SUBF 782                // dst nodes per fine bucket

template<int SUBDIV>
__global__ __launch_bounds__(256) void k_partition(
    const int* __restrict__ dst, const int* __restrict__ src,
    const float* __restrict__ w, int* __restrict__ cur, int2* __restrict__ buf)
{
    __shared__ int2 srt[4096];            // 32 KB staged records
    __shared__ unsigned short bkl[4096];  // 8 KB bucket id per record
    __shared__ int cnt[NSUB];
    __shared__ int excl[NSUB];
    __shared__ int cur2[NSUB];
    __shared__ int resv[NSUB];
    __shared__ int psum[256];
    int tid = threadIdx.x;
    int e0 = blockIdx.x * 4096;
    for (int i = tid; i < NSUB; i += 256) cnt[i] = 0;
    __syncthreads();

    // ---- load + tile histogram ----
    int rb[16]; int2 rv[16];
    #pragma unroll
    for (int i = 0; i < 16; ++i) {
        int e = e0 + i * 256 + tid;
        if (e < NE) {
            int d  = dst[e];
            int bk = d / SUBDIV;
            rb[i]  = bk;
            rv[i]  = make_int2(((d - bk * SUBDIV) << 17) | src[e],
                               __float_as_int(w[e]));
            atomicAdd(&cnt[bk], 1);
        } else rb[i] = -1;
    }
    __syncthreads();

    // ---- scan 512 counts with 256 threads (pairs) + global reserve ----
    int c0 = cnt[2 * tid], c1 = cnt[2 * tid + 1];
    psum[tid] = c0 + c1;
    __syncthreads();
    for (int off = 1; off < 256; off <<= 1) {
        int v = psum[tid];
        if (tid >= off) v += psum[tid - off];
        __syncthreads(); psum[tid] = v; __syncthreads();
    }
    int base = psum[tid] - (c0 + c1);               // exclusive (pair base)
    excl[2 * tid]     = base;
    excl[2 * tid + 1] = base + c0;
    cur2[2 * tid]     = base;
    cur2[2 * tid + 1] = base + c0;
    resv[2 * tid]     = (2 * tid) * CAPB     + atomicAdd(&cur[2 * tid], c0);
    resv[2 * tid + 1] = (2 * tid + 1) * CAPB + atomicAdd(&cur[2 * tid + 1], c1);
    __syncthreads();

    // ---- place into LDS (bucket-contiguous) ----
    #pragma unroll
    for (int i = 0; i < 16; ++i) {
        if (rb[i] >= 0) {
            int p = atomicAdd(&cur2[rb[i]], 1);
            srt[p] = rv[i];
            bkl[p] = (unsigned short)rb[i];
        }
    }
    __syncthreads();

    // ---- line-granular write-out: LDS linear -> global runs ----
    int n = min(NE - e0, 4096);
    for (int i = tid; i < n; i += 256) {
        int bk = bkl[i];
        int g  = resv[bk] + (i - excl[bk]);
        if (g < (bk + 1) * CAPB) buf[g] = srt[i];   // overflow guard
    }
}

// Block = bucket. LDS sort + direct gather; COARSE fuses the 64x64 GEMM.
template<int SUBDIV, int NTOT, bool FINE, bool GEMM>
__global__ __launch_bounds__(1024, 8) void k_sortgather(
    const int2* __restrict__ buf, const int* __restrict__ cur,
    const float* __restrict__ feat,      // x (coarse) or h (fine)
    const int* __restrict__ inv,         // fine only
    const float* __restrict__ W,         // coarse only
    const float* __restrict__ bias,      // coarse only
    float* __restrict__ outp)            // h (coarse) or out (fine)
{
    __shared__ int2 srt[CAPB];           // 32 KB sorted records
    __shared__ int  cnt[SUBDIV];         // per-node cursor/end
    __shared__ int  scn[1024];
    __shared__ float Wl[GEMM ? 4096 : 4];// 16 KB W (coarse only)
    int tid = threadIdx.x;
    int blk = blockIdx.x;
    int nodeLo = blk * SUBDIV;
    int nNodes = min(SUBDIV, NTOT - nodeLo);
    if (nNodes <= 0) return;             // uniform per block
    int lo = blk * CAPB;
    int n  = min(cur[blk], CAPB);        // cur holds the count

    if (GEMM)                            // stage W: one float4 per thread
        ((float4*)Wl)[tid] = ((const float4*)W)[tid];
    for (int i = tid; i < SUBDIV; i += 1024) cnt[i] = 0;
    __syncthreads();

    // ---- load records into regs + LDS hist ----
    int2 r[CAPB / 1024];
    #pragma unroll
    for (int k = 0; k < CAPB / 1024; ++k) {
        int i = k * 1024 + tid;
        if (i < n) { r[k] = buf[lo + i]; atomicAdd(&cnt[r[k].x >> 17], 1); }
        else r[k].x = -1;
    }
    __syncthreads();

    // ---- exclusive scan of node counts (SUBDIV <= 1024) ----
    int v = (tid < SUBDIV) ? cnt[tid] : 0;
    scn[tid] = v; __syncthreads();
    for (int off = 1; off < 1024; off <<= 1) {
        int x = scn[tid];
        if (tid >= off) x += scn[tid - off];
        __syncthreads(); scn[tid] = x; __syncthreads();
    }
    if (tid < SUBDIV) cnt[tid] = scn[tid] - v;   // exclusive -> cursor
    __syncthreads();

    // ---- place into LDS sorted array ----
    #pragma unroll
    for (int k = 0; k < CAPB / 1024; ++k) {
        if (r[k].x >= 0) {
            int p = atomicAdd(&cnt[r[k].x >> 17], 1);
            srt[p] = r[k];
        }
    }
    __syncthreads();                     // cnt[dl] now = inclusive end

    // ---- gather (+ fused GEMM): one 16-lane quadrant per node ----
    int qd = tid >> 4;                   // 0..63
    int ql = tid & 15;
    int c4 = ql << 2;
    int qbase = (tid & 63) & ~15;        // quadrant base lane in wave
    float4 bv = GEMM ? ((const float4*)bias)[ql] : make_float4(0, 0, 0, 0);
    for (int nl = qd; nl < nNodes; nl += 64) {
        int node = nodeLo + nl;
        if (FINE) {
            int iv = inv[node];
            if (iv >= 0) {               // injection: copy h row
                float4 vv = *(const float4*)(feat + (size_t)iv * C + c4);
                *(float4*)(outp + (size_t)node * C + c4) = vv;
                continue;
            }
        }
        int s = (nl == 0) ? 0 : cnt[nl - 1];
        int e = cnt[nl];
        float ax = 0.f, ay = 0.f, az = 0.f, aw = 0.f;
        for (int j = s; j < e; j += 4) {
            int2 q0 = srt[j];
            int2 q1 = (j + 1 < e) ? srt[j + 1] : make_int2(0, 0);
            int2 q2 = (j + 2 < e) ? srt[j + 2] : make_int2(0, 0);
            int2 q3 = (j + 3 < e) ? srt[j + 3] : make_int2(0, 0);
            float4 v0 = *(const float4*)(feat + (size_t)(q0.x & 0x1FFFF) * C + c4);
            float4 v1 = *(const float4*)(feat + (size_t)(q1.x & 0x1FFFF) * C + c4);
            float4 v2 = *(const float4*)(feat + (size_t)(q2.x & 0x1FFFF) * C + c4);
            float4 v3 = *(const float4*)(feat + (size_t)(q3.x & 0x1FFFF) * C + c4);
            float w0 = __int_as_float(q0.y), w1 = __int_as_float(q1.y);
            float w2 = __int_as_float(q2.y), w3 = __int_as_float(q3.y);
            ax = fmaf(w0, v0.x, ax); ay = fmaf(w0, v0.y, ay);
            az = fmaf(w0, v0.z, az); aw = fmaf(w0, v0.w, aw);
            ax = fmaf(w1, v1.x, ax); ay = fmaf(w1, v1.y, ay);
            az = fmaf(w1, v1.z, az); aw = fmaf(w1, v1.w, aw);
            ax = fmaf(w2, v2.x, ax); ay = fmaf(w2, v2.y, ay);
            az = fmaf(w2, v2.z, az); aw = fmaf(w2, v2.w, aw);
            ax = fmaf(w3, v3.x, ax); ay = fmaf(w3, v3.y, ay);
            az = fmaf(w3, v3.z, az); aw = fmaf(w3, v3.w, aw);
        }
        if (!GEMM) {
            *(float4*)(outp + (size_t)node * C + c4) =
                make_float4(ax, ay, az, aw);
        } else {
            // h[node] = agg * W + b: quadrant shuffle-broadcast of agg row.
            // agg[k] lives in lane qbase+(k>>2), component k&3.
            float h0 = bv.x, h1 = bv.y, h2 = bv.z, h3 = bv.w;
            #pragma unroll
            for (int jj = 0; jj < 16; ++jj) {
                float r0 = __shfl(ax, qbase + jj);
                float r1 = __shfl(ay, qbase + jj);
                float r2 = __shfl(az, qbase + jj);
                float r3 = __shfl(aw, qbase + jj);
                float4 w0 = ((const float4*)Wl)[(4 * jj + 0) * 16 + ql];
                float4 w1 = ((const float4*)Wl)[(4 * jj + 1) * 16 + ql];
                float4 w2 = ((const float4*)Wl)[(4 * jj + 2) * 16 + ql];
                float4 w3 = ((const float4*)Wl)[(4 * jj + 3) * 16 + ql];
                h0 = fmaf(r0, w0.x, h0); h1 = fmaf(r0, w0.y, h1);
                h2 = fmaf(r0, w0.z, h2); h3 = fmaf(r0, w0.w, h3);
                h0 = fmaf(r1, w1.x, h0); h1 = fmaf(r1, w1.y, h1);
                h2 = fmaf(r1, w1.z, h2); h3 = fmaf(r1, w1.w, h3);
                h0 = fmaf(r2, w2.x, h0); h1 = fmaf(r2, w2.y, h1);
                h2 = fmaf(r2, w2.z, h2); h3 = fmaf(r2, w2.w, h3);
                h0 = fmaf(r3, w3.x, h0); h1 = fmaf(r3, w3.y, h1);
                h2 = fmaf(r3, w3.z, h2); h3 = fmaf(r3, w3.w, h3);
            }
            *(float4*)(outp + (size_t)node * C + c4) =
                make_float4(h0, h1, h2, h3);
        }
    }
}

// inv scatter + zero both cursor arrays (block 0).
__global__ __launch_bounds__(256) void k_inv(
    const int* __restrict__ fwd, int* __restrict__ inv, int* __restrict__ cur)
{
    int i = blockIdx.x * 256 + threadIdx.x;
    if (i < NC) inv[fwd[i]] = i;
    if (blockIdx.x == 0)
        for (int j = threadIdx.x; j < 2 * NSUB; j += 256) cur[j] = 0;
}

extern "C" void kernel_launch(void* const* d_in, const int* in_sizes, int n_in,
                              void* d_out, int out_size, void* d_ws, size_t ws_size,
                              hipStream_t stream) {
    const float* x    = (const float*)d_in[0];
    const float* W    = (const float*)d_in[1];
    const float* b    = (const float*)d_in[2];
    const int*   ei   = (const int*)d_in[3];   // [2,E]: src = ei, dst = ei+NE
    const float* ea   = (const float*)d_in[4];
    const int*   psrc = (const int*)d_in[5];
    const int*   pdst = (const int*)d_in[6];
    const float* pw   = (const float*)d_in[7];
    const int*   fwd  = (const int*)d_in[8];
    float* out = (float*)d_out;

    // Workspace (~44 MB): h 25.6 | buf 16.8 | inv 1.6 | curC+curF (adjacent)
    char* p = (char*)d_ws;
    float* h   = (float*)p;  p += (size_t)NC * C * sizeof(float);        // 25.6 MB
    int2*  buf = (int2*)p;   p += (size_t)NSUB * CAPB * sizeof(int2);    // 16.8 MB
    int*   inv = (int*)p;    p += (size_t)NF * sizeof(int);              // 1.6 MB
    int*   curC = (int*)p;   p += NSUB * sizeof(int);
    int*   curF = (int*)p;   p += NSUB * sizeof(int);

    const int nTiles = (NE + 4095) / 4096;        // 391

    // inv map + cursor zeroing (one dispatch)
    hipMemsetAsync(inv, 0xFF, (size_t)NF * sizeof(int), stream);
    k_inv<<<(NC + 255) / 256, 256, 0, stream>>>(fwd, inv, curC);

    // ---- coarse: partition -> fused sort+gather+GEMM -> h ----
    k_partition<SUBC><<<nTiles, 256, 0, stream>>>(ei + NE, ei, ea, curC, buf);
    k_sortgather<SUBC, NC, false, true><<<NSUB, 1024, 0, stream>>>(
        buf, curC, x, nullptr, W, b, h);

    // ---- fine: partition (reuses buf) -> fused sort+gather+inject -> out ----
    k_partition<SUBF><<<nTiles, 256, 0, stream>>>(pdst, psrc, pw, curF, buf);
    k_sortgather<SUBF, NF, true, false><<<NSUB, 1024, 0, stream>>>(
        buf, curF, h, inv, nullptr, nullptr, out);
}

// Round 7
// 373.348 us; speedup vs baseline: 2.0314x; 2.0314x over previous
//
#include <hip/hip_runtime.h>

#define NC 100000
#define NF 400000
#define NE 1600000
#define C  64

// ============================================================================
// v8 = v6 (363us, proven) with ONLY the partition replaced by the LDS-staged
// line-granular version. Round-6's GEMM fusion is reverted: under
// launch_bounds(1024,8) the epilogue spilled to scratch (FETCH 943MB /
// WRITE 511MB, 20x amplification, 508us). GEMM stays a separate (256,1)
// kernel where the allocator may use ~512 VGPRs and W stays resident.
//  k_partition  : per 4096-edge tile: LDS hist(512) -> pair-scan ->
//                 place into LDS srt[] (+u16 bucket ids) -> 1 global
//                 reserve atomic per bucket -> LINEAR sweep writes full
//                 64B lines (v6 wrote 8B scattered: up to 64 line
//                 transactions per wave; now ~8).
//  k_sortgather : EXACT v6 kernel (VGPR=20, no spill: round-5 FETCH
//                 matched useful traffic).
//  k_gemm_ip    : EXACT v6 kernel ((256,1), 2-row ILP).
// ============================================================================

#define NSUB 512                // buckets per phase
#define CAPB 4096               // records per bucket (mean ~3130)
#define SUBC 196                // dst nodes per coarse bucket
#define SUBF 782                // dst nodes per fine bucket

template<int SUBDIV>
__global__ __launch_bounds__(256) void k_partition(
    const int* __restrict__ dst, const int* __restrict__ src,
    const float* __restrict__ w, int* __restrict__ cur, int2* __restrict__ buf)
{
    __shared__ int2 srt[4096];            // 32 KB staged records
    __shared__ unsigned short bkl[4096];  // 8 KB bucket id per record
    __shared__ int cnt[NSUB];
    __shared__ int excl[NSUB];
    __shared__ int cur2[NSUB];
    __shared__ int resv[NSUB];
    __shared__ int psum[256];
    int tid = threadIdx.x;
    int e0 = blockIdx.x * 4096;
    for (int i = tid; i < NSUB; i += 256) cnt[i] = 0;
    __syncthreads();

    // ---- load + tile histogram ----
    int rb[16]; int2 rv[16];
    #pragma unroll
    for (int i = 0; i < 16; ++i) {
        int e = e0 + i * 256 + tid;
        if (e < NE) {
            int d  = dst[e];
            int bk = d / SUBDIV;
            rb[i]  = bk;
            rv[i]  = make_int2(((d - bk * SUBDIV) << 17) | src[e],
                               __float_as_int(w[e]));
            atomicAdd(&cnt[bk], 1);
        } else rb[i] = -1;
    }
    __syncthreads();

    // ---- scan 512 counts with 256 threads (pairs) + global reserve ----
    int c0 = cnt[2 * tid], c1 = cnt[2 * tid + 1];
    psum[tid] = c0 + c1;
    __syncthreads();
    for (int off = 1; off < 256; off <<= 1) {
        int v = psum[tid];
        if (tid >= off) v += psum[tid - off];
        __syncthreads(); psum[tid] = v; __syncthreads();
    }
    int base = psum[tid] - (c0 + c1);               // exclusive (pair base)
    excl[2 * tid]     = base;
    excl[2 * tid + 1] = base + c0;
    cur2[2 * tid]     = base;
    cur2[2 * tid + 1] = base + c0;
    resv[2 * tid]     = (2 * tid) * CAPB     + atomicAdd(&cur[2 * tid], c0);
    resv[2 * tid + 1] = (2 * tid + 1) * CAPB + atomicAdd(&cur[2 * tid + 1], c1);
    __syncthreads();

    // ---- place into LDS (bucket-contiguous) ----
    #pragma unroll
    for (int i = 0; i < 16; ++i) {
        if (rb[i] >= 0) {
            int p = atomicAdd(&cur2[rb[i]], 1);
            srt[p] = rv[i];
            bkl[p] = (unsigned short)rb[i];
        }
    }
    __syncthreads();

    // ---- line-granular write-out: LDS linear -> global runs ----
    int n = min(NE - e0, 4096);
    for (int i = tid; i < n; i += 256) {
        int bk = bkl[i];
        int g  = resv[bk] + (i - excl[bk]);
        if (g < (bk + 1) * CAPB) buf[g] = srt[i];   // overflow guard
    }
}

// Block = bucket. LDS sort + direct gather; no global CSR. (exact v6)
template<int SUBDIV, int NTOT, bool FINE>
__global__ __launch_bounds__(1024, 8) void k_sortgather(
    const int2* __restrict__ buf, const int* __restrict__ cur,
    const float* __restrict__ feat,      // x (coarse) or h (fine)
    const int* __restrict__ inv,         // fine only
    float* __restrict__ outp)            // h/agg (coarse) or out (fine)
{
    __shared__ int2 srt[CAPB];           // 32 KB sorted records
    __shared__ int  cnt[SUBDIV];         // per-node cursor/end
    __shared__ int  scn[1024];
    int tid = threadIdx.x;
    int blk = blockIdx.x;
    int nodeLo = blk * SUBDIV;
    int nNodes = min(SUBDIV, NTOT - nodeLo);
    if (nNodes <= 0) return;             // uniform per block
    int lo = blk * CAPB;
    int n  = min(cur[blk], CAPB);        // cur holds the count

    for (int i = tid; i < SUBDIV; i += 1024) cnt[i] = 0;
    __syncthreads();

    // ---- load records into regs + LDS hist ----
    int2 r[CAPB / 1024];
    #pragma unroll
    for (int k = 0; k < CAPB / 1024; ++k) {
        int i = k * 1024 + tid;
        if (i < n) { r[k] = buf[lo + i]; atomicAdd(&cnt[r[k].x >> 17], 1); }
        else r[k].x = -1;
    }
    __syncthreads();

    // ---- exclusive scan of node counts (SUBDIV <= 1024) ----
    int v = (tid < SUBDIV) ? cnt[tid] : 0;
    scn[tid] = v; __syncthreads();
    for (int off = 1; off < 1024; off <<= 1) {
        int x = scn[tid];
        if (tid >= off) x += scn[tid - off];
        __syncthreads(); scn[tid] = x; __syncthreads();
    }
    if (tid < SUBDIV) cnt[tid] = scn[tid] - v;   // exclusive -> cursor
    __syncthreads();

    // ---- place into LDS sorted array ----
    #pragma unroll
    for (int k = 0; k < CAPB / 1024; ++k) {
        if (r[k].x >= 0) {
            int p = atomicAdd(&cnt[r[k].x >> 17], 1);
            srt[p] = r[k];
        }
    }
    __syncthreads();                     // cnt[dl] now = inclusive end

    // ---- gather: one 16-lane quadrant per node ----
    int qd = tid >> 4;                   // 0..63
    int c4 = (tid & 15) << 2;
    for (int nl = qd; nl < nNodes; nl += 64) {
        int node = nodeLo + nl;
        if (FINE) {
            int iv = inv[node];
            if (iv >= 0) {               // injection: copy h row
                float4 vv = *(const float4*)(feat + (size_t)iv * C + c4);
                *(float4*)(outp + (size_t)node * C + c4) = vv;
                continue;
            }
        }
        int s = (nl == 0) ? 0 : cnt[nl - 1];
        int e = cnt[nl];
        float ax = 0.f, ay = 0.f, az = 0.f, aw = 0.f;
        for (int j = s; j < e; j += 4) {
            int2 q0 = srt[j];
            int2 q1 = (j + 1 < e) ? srt[j + 1] : make_int2(0, 0);
            int2 q2 = (j + 2 < e) ? srt[j + 2] : make_int2(0, 0);
            int2 q3 = (j + 3 < e) ? srt[j + 3] : make_int2(0, 0);
            float4 v0 = *(const float4*)(feat + (size_t)(q0.x & 0x1FFFF) * C + c4);
            float4 v1 = *(const float4*)(feat + (size_t)(q1.x & 0x1FFFF) * C + c4);
            float4 v2 = *(const float4*)(feat + (size_t)(q2.x & 0x1FFFF) * C + c4);
            float4 v3 = *(const float4*)(feat + (size_t)(q3.x & 0x1FFFF) * C + c4);
            float w0 = __int_as_float(q0.y), w1 = __int_as_float(q1.y);
            float w2 = __int_as_float(q2.y), w3 = __int_as_float(q3.y);
            ax = fmaf(w0, v0.x, ax); ay = fmaf(w0, v0.y, ay);
            az = fmaf(w0, v0.z, az); aw = fmaf(w0, v0.w, aw);
            ax = fmaf(w1, v1.x, ax); ay = fmaf(w1, v1.y, ay);
            az = fmaf(w1, v1.z, az); aw = fmaf(w1, v1.w, aw);
            ax = fmaf(w2, v2.x, ax); ay = fmaf(w2, v2.y, ay);
            az = fmaf(w2, v2.z, az); aw = fmaf(w2, v2.w, aw);
            ax = fmaf(w3, v3.x, ax); ay = fmaf(w3, v3.y, ay);
            az = fmaf(w3, v3.z, az); aw = fmaf(w3, v3.w, aw);
        }
        *(float4*)(outp + (size_t)node * C + c4) = make_float4(ax, ay, az, aw);
    }
}

// GEMM: (256,1) -> allocator keeps wreg[64] resident; 2-row ILP. (exact v6)
__global__ __launch_bounds__(256, 1) void k_gemm_ip(
    float* __restrict__ h, const float* __restrict__ W, const float* __restrict__ b)
{
    int tid = threadIdx.x;
    int lane = tid & 63;
    float wreg[64];
    #pragma unroll
    for (int k = 0; k < 64; ++k) wreg[k] = W[k * C + lane];
    float bl = b[lane];
    int wv = (blockIdx.x * 256 + tid) >> 6;
    int nW = gridDim.x * 4;
    for (int row = wv; row < NC; row += 2 * nW) {
        int row2 = row + nW;
        bool has2 = row2 < NC;
        int row2c = has2 ? row2 : row;           // safe dup-load on tail
        float* ar  = h + (size_t)row * C;
        float* ar2 = h + (size_t)row2c * C;
        float acc = bl, acc2 = bl;
        #pragma unroll
        for (int kk = 0; kk < 16; ++kk) {
            float4 a4 = *(const float4*)(ar + 4 * kk);
            float4 b4 = *(const float4*)(ar2 + 4 * kk);
            acc  = fmaf(a4.x, wreg[4 * kk + 0], acc);
            acc  = fmaf(a4.y, wreg[4 * kk + 1], acc);
            acc  = fmaf(a4.z, wreg[4 * kk + 2], acc);
            acc  = fmaf(a4.w, wreg[4 * kk + 3], acc);
            acc2 = fmaf(b4.x, wreg[4 * kk + 0], acc2);
            acc2 = fmaf(b4.y, wreg[4 * kk + 1], acc2);
            acc2 = fmaf(b4.z, wreg[4 * kk + 2], acc2);
            acc2 = fmaf(b4.w, wreg[4 * kk + 3], acc2);
        }
        ar[lane] = acc;
        if (has2) ar2[lane] = acc2;
    }
}

// inv scatter + zero both cursor arrays (block 0).
__global__ __launch_bounds__(256) void k_inv(
    const int* __restrict__ fwd, int* __restrict__ inv, int* __restrict__ cur)
{
    int i = blockIdx.x * 256 + threadIdx.x;
    if (i < NC) inv[fwd[i]] = i;
    if (blockIdx.x == 0)
        for (int j = threadIdx.x; j < 2 * NSUB; j += 256) cur[j] = 0;
}

extern "C" void kernel_launch(void* const* d_in, const int* in_sizes, int n_in,
                              void* d_out, int out_size, void* d_ws, size_t ws_size,
                              hipStream_t stream) {
    const float* x    = (const float*)d_in[0];
    const float* W    = (const float*)d_in[1];
    const float* b    = (const float*)d_in[2];
    const int*   ei   = (const int*)d_in[3];   // [2,E]: src = ei, dst = ei+NE
    const float* ea   = (const float*)d_in[4];
    const int*   psrc = (const int*)d_in[5];
    const int*   pdst = (const int*)d_in[6];
    const float* pw   = (const float*)d_in[7];
    const int*   fwd  = (const int*)d_in[8];
    float* out = (float*)d_out;

    // Workspace (~44 MB): h 25.6 | buf 16.8 | inv 1.6 | curC+curF (adjacent)
    char* p = (char*)d_ws;
    float* h   = (float*)p;  p += (size_t)NC * C * sizeof(float);        // 25.6 MB
    int2*  buf = (int2*)p;   p += (size_t)NSUB * CAPB * sizeof(int2);    // 16.8 MB
    int*   inv = (int*)p;    p += (size_t)NF * sizeof(int);              // 1.6 MB
    int*   curC = (int*)p;   p += NSUB * sizeof(int);
    int*   curF = (int*)p;   p += NSUB * sizeof(int);

    const int nTiles = (NE + 4095) / 4096;        // 391

    // inv map + cursor zeroing (one dispatch)
    hipMemsetAsync(inv, 0xFF, (size_t)NF * sizeof(int), stream);
    k_inv<<<(NC + 255) / 256, 256, 0, stream>>>(fwd, inv, curC);

    // ---- coarse: partition -> fused sort+gather (agg -> h), then GEMM ----
    k_partition<SUBC><<<nTiles, 256, 0, stream>>>(ei + NE, ei, ea, curC, buf);
    k_sortgather<SUBC, NC, false><<<NSUB, 1024, 0, stream>>>(
        buf, curC, x, nullptr, h);
    k_gemm_ip<<<2048, 256, 0, stream>>>(h, W, b);

    // ---- fine: partition (reuses buf) -> fused sort+gather+inject -> out ----
    k_partition<SUBF><<<nTiles, 256, 0, stream>>>(pdst, psrc, pw, curF, buf);
    k_sortgather<SUBF, NF, true><<<NSUB, 1024, 0, stream>>>(
        buf, curF, h, inv, out);
}

// Round 8
// 351.254 us; speedup vs baseline: 2.1592x; 1.0629x over previous
//
#include <hip/hip_runtime.h>

#define NC 100000
#define NF 400000
#define NE 1600000
#define C  64

// ============================================================================
// v9 = v8 with (1) partition reverted to v6-style direct scatter and both
// phases MERGED into one dispatch (disjoint buffers, 782 blocks), and
// (2) k_gemm_ip replaced by a 64x64 LDS-tiled GEMM.
// Round-7 accounting: sortgathers 2x65us are near their structural per-XCD
// unique-row fetch bound; the hidden ~120us is partitions (~60 each) and
// gemm still ~50us (v5->v6 only moved -14us: the (256,1) W-in-VGPR fix
// never took; the kernel was L1-BW bound re-streaming 16KB of W per row).
//  k_gemm_tile : block = 64 rows. x-tile + W staged in LDS (pad 68 floats
//                -> only broadcasts/2-way conflicts, free per m136).
//                16x16 thread grid, 4x4 outputs/thread, b128 LDS reads,
//                1024 FMA / 128 LDS-instr per thread. W LDS traffic per
//                row: 4KB (vs 16KB L1 traffic before).
//  k_part2     : blocks [0,391) coarse, [391,782) fine. v6 body: LDS
//                bucket-count -> 1 reserve atomic per bucket -> scatter.
// ============================================================================

#define NSUB 512                // buckets per phase
#define CAPB 4096               // records per bucket (mean ~3130, +17 sigma)
#define SUBC 196                // dst nodes per coarse bucket
#define SUBF 782                // dst nodes per fine bucket
#define NTILES ((NE + 4095) / 4096)   // 391

template<int SUBDIV>
__device__ __forceinline__ void part_tile(
    const int* __restrict__ dst, const int* __restrict__ src,
    const float* __restrict__ w, int* __restrict__ cur, int2* __restrict__ buf,
    int tile, int* lcnt)
{
    int tid = threadIdx.x;
    int e0 = tile * 4096;
    for (int i = tid; i < NSUB; i += 256) lcnt[i] = 0;
    __syncthreads();
    int rb[16]; int2 rv[16];
    #pragma unroll
    for (int i = 0; i < 16; ++i) {
        int e = e0 + i * 256 + tid;
        if (e < NE) {
            int d  = dst[e];
            int bk = d / SUBDIV;
            rb[i]  = bk;
            rv[i]  = make_int2(((d - bk * SUBDIV) << 17) | src[e],
                               __float_as_int(w[e]));
            atomicAdd(&lcnt[bk], 1);
        } else rb[i] = -1;
    }
    __syncthreads();
    for (int i = tid; i < NSUB; i += 256)
        lcnt[i] = i * CAPB + atomicAdd(&cur[i], lcnt[i]);
    __syncthreads();
    #pragma unroll
    for (int i = 0; i < 16; ++i) {
        if (rb[i] >= 0) {
            int p = atomicAdd(&lcnt[rb[i]], 1);
            if (p < (rb[i] + 1) * CAPB) buf[p] = rv[i];   // overflow guard
        }
    }
}

__global__ __launch_bounds__(256) void k_part2(
    const int* __restrict__ cd, const int* __restrict__ cs,
    const float* __restrict__ cw,
    const int* __restrict__ pd, const int* __restrict__ ps,
    const float* __restrict__ pw,
    int* __restrict__ curC, int* __restrict__ curF,
    int2* __restrict__ bufC, int2* __restrict__ bufF)
{
    __shared__ int lcnt[NSUB];
    if (blockIdx.x < NTILES)
        part_tile<SUBC>(cd, cs, cw, curC, bufC, blockIdx.x, lcnt);
    else
        part_tile<SUBF>(pd, ps, pw, curF, bufF, blockIdx.x - NTILES, lcnt);
}

// Block = bucket. LDS sort + direct gather; no global CSR. (exact v6)
template<int SUBDIV, int NTOT, bool FINE>
__global__ __launch_bounds__(1024, 8) void k_sortgather(
    const int2* __restrict__ buf, const int* __restrict__ cur,
    const float* __restrict__ feat,      // x (coarse) or h (fine)
    const int* __restrict__ inv,         // fine only
    float* __restrict__ outp)            // h/agg (coarse) or out (fine)
{
    __shared__ int2 srt[CAPB];           // 32 KB sorted records
    __shared__ int  cnt[SUBDIV];         // per-node cursor/end
    __shared__ int  scn[1024];
    int tid = threadIdx.x;
    int blk = blockIdx.x;
    int nodeLo = blk * SUBDIV;
    int nNodes = min(SUBDIV, NTOT - nodeLo);
    if (nNodes <= 0) return;             // uniform per block
    int lo = blk * CAPB;
    int n  = min(cur[blk], CAPB);        // cur holds the count

    for (int i = tid; i < SUBDIV; i += 1024) cnt[i] = 0;
    __syncthreads();

    // ---- load records into regs + LDS hist ----
    int2 r[CAPB / 1024];
    #pragma unroll
    for (int k = 0; k < CAPB / 1024; ++k) {
        int i = k * 1024 + tid;
        if (i < n) { r[k] = buf[lo + i]; atomicAdd(&cnt[r[k].x >> 17], 1); }
        else r[k].x = -1;
    }
    __syncthreads();

    // ---- exclusive scan of node counts (SUBDIV <= 1024) ----
    int v = (tid < SUBDIV) ? cnt[tid] : 0;
    scn[tid] = v; __syncthreads();
    for (int off = 1; off < 1024; off <<= 1) {
        int x = scn[tid];
        if (tid >= off) x += scn[tid - off];
        __syncthreads(); scn[tid] = x; __syncthreads();
    }
    if (tid < SUBDIV) cnt[tid] = scn[tid] - v;   // exclusive -> cursor
    __syncthreads();

    // ---- place into LDS sorted array ----
    #pragma unroll
    for (int k = 0; k < CAPB / 1024; ++k) {
        if (r[k].x >= 0) {
            int p = atomicAdd(&cnt[r[k].x >> 17], 1);
            srt[p] = r[k];
        }
    }
    __syncthreads();                     // cnt[dl] now = inclusive end

    // ---- gather: one 16-lane quadrant per node ----
    int qd = tid >> 4;                   // 0..63
    int c4 = (tid & 15) << 2;
    for (int nl = qd; nl < nNodes; nl += 64) {
        int node = nodeLo + nl;
        if (FINE) {
            int iv = inv[node];
            if (iv >= 0) {               // injection: copy h row
                float4 vv = *(const float4*)(feat + (size_t)iv * C + c4);
                *(float4*)(outp + (size_t)node * C + c4) = vv;
                continue;
            }
        }
        int s = (nl == 0) ? 0 : cnt[nl - 1];
        int e = cnt[nl];
        float ax = 0.f, ay = 0.f, az = 0.f, aw = 0.f;
        for (int j = s; j < e; j += 4) {
            int2 q0 = srt[j];
            int2 q1 = (j + 1 < e) ? srt[j + 1] : make_int2(0, 0);
            int2 q2 = (j + 2 < e) ? srt[j + 2] : make_int2(0, 0);
            int2 q3 = (j + 3 < e) ? srt[j + 3] : make_int2(0, 0);
            float4 v0 = *(const float4*)(feat + (size_t)(q0.x & 0x1FFFF) * C + c4);
            float4 v1 = *(const float4*)(feat + (size_t)(q1.x & 0x1FFFF) * C + c4);
            float4 v2 = *(const float4*)(feat + (size_t)(q2.x & 0x1FFFF) * C + c4);
            float4 v3 = *(const float4*)(feat + (size_t)(q3.x & 0x1FFFF) * C + c4);
            float w0 = __int_as_float(q0.y), w1 = __int_as_float(q1.y);
            float w2 = __int_as_float(q2.y), w3 = __int_as_float(q3.y);
            ax = fmaf(w0, v0.x, ax); ay = fmaf(w0, v0.y, ay);
            az = fmaf(w0, v0.z, az); aw = fmaf(w0, v0.w, aw);
            ax = fmaf(w1, v1.x, ax); ay = fmaf(w1, v1.y, ay);
            az = fmaf(w1, v1.z, az); aw = fmaf(w1, v1.w, aw);
            ax = fmaf(w2, v2.x, ax); ay = fmaf(w2, v2.y, ay);
            az = fmaf(w2, v2.z, az); aw = fmaf(w2, v2.w, aw);
            ax = fmaf(w3, v3.x, ax); ay = fmaf(w3, v3.y, ay);
            az = fmaf(w3, v3.z, az); aw = fmaf(w3, v3.w, aw);
        }
        *(float4*)(outp + (size_t)node * C + c4) = make_float4(ax, ay, az, aw);
    }
}

// Tiled GEMM: h[64 rows] = h[64 rows] @ W + b, x-tile + W in LDS.
// 16x16 threads, 4 rows x 4 cols per thread, all LDS reads are
// broadcast or 2-way (free). In-place safe: block owns its rows.
__global__ __launch_bounds__(256) void k_gemm_tile(
    float* __restrict__ h, const float* __restrict__ W,
    const float* __restrict__ bias)
{
    __shared__ float xs[64][68];
    __shared__ float ws[64][68];
    __shared__ float bs[64];
    int tid = threadIdx.x;
    int r0 = blockIdx.x * 64;

    // stage W + bias + x-tile (all float4, 16B-aligned: 68*4=272=17*16)
    for (int i = tid; i < 1024; i += 256) {
        int k = i >> 4, c = (i & 15) << 2;
        *(float4*)&ws[k][c] = ((const float4*)W)[i];
        int r = r0 + k;
        float4 xv = (r < NC) ? *(const float4*)(h + (size_t)r * C + c)
                             : make_float4(0, 0, 0, 0);
        *(float4*)&xs[k][c] = xv;
    }
    if (tid < 64) bs[tid] = bias[tid];
    __syncthreads();

    int tr = tid >> 4;                   // 0..15 -> rows tr*4..tr*4+3
    int tc = tid & 15;                   // 0..15 -> cols tc*4..tc*4+3
    float4 a0 = make_float4(0, 0, 0, 0), a1 = a0, a2 = a0, a3 = a0;
    #pragma unroll
    for (int kk = 0; kk < 16; ++kk) {
        int k = kk << 2;
        float4 x0 = *(const float4*)&xs[tr * 4 + 0][k];
        float4 x1 = *(const float4*)&xs[tr * 4 + 1][k];
        float4 x2 = *(const float4*)&xs[tr * 4 + 2][k];
        float4 x3 = *(const float4*)&xs[tr * 4 + 3][k];
        float4 w0 = *(const float4*)&ws[k + 0][tc * 4];
        float4 w1 = *(const float4*)&ws[k + 1][tc * 4];
        float4 w2 = *(const float4*)&ws[k + 2][tc * 4];
        float4 w3 = *(const float4*)&ws[k + 3][tc * 4];
        a0.x = fmaf(x0.x, w0.x, a0.x); a0.y = fmaf(x0.x, w0.y, a0.y);
        a0.z = fmaf(x0.x, w0.z, a0.z); a0.w = fmaf(x0.x, w0.w, a0.w);
        a0.x = fmaf(x0.y, w1.x, a0.x); a0.y = fmaf(x0.y, w1.y, a0.y);
        a0.z = fmaf(x0.y, w1.z, a0.z); a0.w = fmaf(x0.y, w1.w, a0.w);
        a0.x = fmaf(x0.z, w2.x, a0.x); a0.y = fmaf(x0.z, w2.y, a0.y);
        a0.z = fmaf(x0.z, w2.z, a0.z); a0.w = fmaf(x0.z, w2.w, a0.w);
        a0.x = fmaf(x0.w, w3.x, a0.x); a0.y = fmaf(x0.w, w3.y, a0.y);
        a0.z = fmaf(x0.w, w3.z, a0.z); a0.w = fmaf(x0.w, w3.w, a0.w);
        a1.x = fmaf(x1.x, w0.x, a1.x); a1.y = fmaf(x1.x, w0.y, a1.y);
        a1.z = fmaf(x1.x, w0.z, a1.z); a1.w = fmaf(x1.x, w0.w, a1.w);
        a1.x = fmaf(x1.y, w1.x, a1.x); a1.y = fmaf(x1.y, w1.y, a1.y);
        a1.z = fmaf(x1.y, w1.z, a1.z); a1.w = fmaf(x1.y, w1.w, a1.w);
        a1.x = fmaf(x1.z, w2.x, a1.x); a1.y = fmaf(x1.z, w2.y, a1.y);
        a1.z = fmaf(x1.z, w2.z, a1.z); a1.w = fmaf(x1.z, w2.w, a1.w);
        a1.x = fmaf(x1.w, w3.x, a1.x); a1.y = fmaf(x1.w, w3.y, a1.y);
        a1.z = fmaf(x1.w, w3.z, a1.z); a1.w = fmaf(x1.w, w3.w, a1.w);
        a2.x = fmaf(x2.x, w0.x, a2.x); a2.y = fmaf(x2.x, w0.y, a2.y);
        a2.z = fmaf(x2.x, w0.z, a2.z); a2.w = fmaf(x2.x, w0.w, a2.w);
        a2.x = fmaf(x2.y, w1.x, a2.x); a2.y = fmaf(x2.y, w1.y, a2.y);
        a2.z = fmaf(x2.y, w1.z, a2.z); a2.w = fmaf(x2.y, w1.w, a2.w);
        a2.x = fmaf(x2.z, w2.x, a2.x); a2.y = fmaf(x2.z, w2.y, a2.y);
        a2.z = fmaf(x2.z, w2.z, a2.z); a2.w = fmaf(x2.z, w2.w, a2.w);
        a2.x = fmaf(x2.w, w3.x, a2.x); a2.y = fmaf(x2.w, w3.y, a2.y);
        a2.z = fmaf(x2.w, w3.z, a2.z); a2.w = fmaf(x2.w, w3.w, a2.w);
        a3.x = fmaf(x3.x, w0.x, a3.x); a3.y = fmaf(x3.x, w0.y, a3.y);
        a3.z = fmaf(x3.x, w0.z, a3.z); a3.w = fmaf(x3.x, w0.w, a3.w);
        a3.x = fmaf(x3.y, w1.x, a3.x); a3.y = fmaf(x3.y, w1.y, a3.y);
        a3.z = fmaf(x3.y, w1.z, a3.z); a3.w = fmaf(x3.y, w1.w, a3.w);
        a3.x = fmaf(x3.z, w2.x, a3.x); a3.y = fmaf(x3.z, w2.y, a3.y);
        a3.z = fmaf(x3.z, w2.z, a3.z); a3.w = fmaf(x3.z, w2.w, a3.w);
        a3.x = fmaf(x3.w, w3.x, a3.x); a3.y = fmaf(x3.w, w3.y, a3.y);
        a3.z = fmaf(x3.w, w3.z, a3.z); a3.w = fmaf(x3.w, w3.w, a3.w);
    }
    float4 bv = *(const float4*)&bs[tc * 4];
    a0.x += bv.x; a0.y += bv.y; a0.z += bv.z; a0.w += bv.w;
    a1.x += bv.x; a1.y += bv.y; a1.z += bv.z; a1.w += bv.w;
    a2.x += bv.x; a2.y += bv.y; a2.z += bv.z; a2.w += bv.w;
    a3.x += bv.x; a3.y += bv.y; a3.z += bv.z; a3.w += bv.w;
    int rb = r0 + tr * 4;
    if (rb + 0 < NC) *(float4*)(h + (size_t)(rb + 0) * C + tc * 4) = a0;
    if (rb + 1 < NC) *(float4*)(h + (size_t)(rb + 1) * C + tc * 4) = a1;
    if (rb + 2 < NC) *(float4*)(h + (size_t)(rb + 2) * C + tc * 4) = a2;
    if (rb + 3 < NC) *(float4*)(h + (size_t)(rb + 3) * C + tc * 4) = a3;
}

// inv scatter + zero both cursor arrays (block 0).
__global__ __launch_bounds__(256) void k_inv(
    const int* __restrict__ fwd, int* __restrict__ inv, int* __restrict__ cur)
{
    int i = blockIdx.x * 256 + threadIdx.x;
    if (i < NC) inv[fwd[i]] = i;
    if (blockIdx.x == 0)
        for (int j = threadIdx.x; j < 2 * NSUB; j += 256) cur[j] = 0;
}

extern "C" void kernel_launch(void* const* d_in, const int* in_sizes, int n_in,
                              void* d_out, int out_size, void* d_ws, size_t ws_size,
                              hipStream_t stream) {
    const float* x    = (const float*)d_in[0];
    const float* W    = (const float*)d_in[1];
    const float* b    = (const float*)d_in[2];
    const int*   ei   = (const int*)d_in[3];   // [2,E]: src = ei, dst = ei+NE
    const float* ea   = (const float*)d_in[4];
    const int*   psrc = (const int*)d_in[5];
    const int*   pdst = (const int*)d_in[6];
    const float* pw   = (const float*)d_in[7];
    const int*   fwd  = (const int*)d_in[8];
    float* out = (float*)d_out;

    // Workspace (~54 MB): h 25.6 | bufC 16.8 | bufF 16.8 reused? NO — both
    // live simultaneously now: h 25.6 + bufC 16.8 + bufF 16.8 = 59.2 > 55?
    // bufC is dead after sgC; bufF written by k_part2 BEFORE sgC runs, so
    // both must coexist: place bufF AFTER h's region is NOT possible (h
    // written by sgC while bufF still needed by sgF). Layout: h | bufC |
    // bufF | inv | cur. Total 25.6+16.8+16.8+1.6 = 60.8 MB.
    char* p = (char*)d_ws;
    float* h    = (float*)p;  p += (size_t)NC * C * sizeof(float);       // 25.6 MB
    int2*  bufC = (int2*)p;   p += (size_t)NSUB * CAPB * sizeof(int2);   // 16.8 MB
    int2*  bufF = (int2*)p;   p += (size_t)NSUB * CAPB * sizeof(int2);   // 16.8 MB
    int*   inv  = (int*)p;    p += (size_t)NF * sizeof(int);             // 1.6 MB
    int*   curC = (int*)p;    p += NSUB * sizeof(int);
    int*   curF = (int*)p;    p += NSUB * sizeof(int);

    // inv map + cursor zeroing (one dispatch)
    hipMemsetAsync(inv, 0xFF, (size_t)NF * sizeof(int), stream);
    k_inv<<<(NC + 255) / 256, 256, 0, stream>>>(fwd, inv, curC);

    // ---- both partitions in one dispatch (independent work) ----
    k_part2<<<2 * NTILES, 256, 0, stream>>>(ei + NE, ei, ea, pdst, psrc, pw,
                                            curC, curF, bufC, bufF);

    // ---- coarse: fused sort+gather (agg -> h), then tiled GEMM ----
    k_sortgather<SUBC, NC, false><<<NSUB, 1024, 0, stream>>>(
        bufC, curC, x, nullptr, h);
    k_gemm_tile<<<(NC + 63) / 64, 256, 0, stream>>>(h, W, b);

    // ---- fine: fused sort+gather+inject -> out ----
    k_sortgather<SUBF, NF, true><<<NSUB, 1024, 0, stream>>>(
        bufF, curF, h, inv, out);
}